// Round 18
// baseline (418.389 us; speedup 1.0000x reference)
//
#include <hip/hip_runtime.h>
#include <math.h>
#include <float.h>

#define NPTS 4096
#define KNN  20
#define RPW  2                  // rows per wave
#define WAVES 16                // waves per block (1024 threads)
#define ROWSB (WAVES * RPW)     // 32 rows per block
#define NCHUNK (NPTS / 256)     // 16 chunks of 256 candidates (4 per lane)

#define ROW_SHR1    0x111
#define ROW_SHR2    0x112
#define ROW_SHR4    0x114
#define ROW_SHR8    0x118
#define ROW_BCAST15 0x142
#define ROW_BCAST31 0x143

template <int CTRL>
__device__ __forceinline__ float dpp_mv(float x, float ident) {
    int r = __builtin_amdgcn_update_dpp(__float_as_int(ident), __float_as_int(x),
                                        CTRL, 0xf, 0xf, false);
    return __int_as_float(r);
}
__device__ __forceinline__ float readlane_f(float v, int l) {
    return __int_as_float(__builtin_amdgcn_readlane(__float_as_int(v), l));
}
__device__ __forceinline__ float wave_min_bcast(float v) {
    v = fminf(v, dpp_mv<ROW_SHR1>(v, FLT_MAX));
    v = fminf(v, dpp_mv<ROW_SHR2>(v, FLT_MAX));
    v = fminf(v, dpp_mv<ROW_SHR4>(v, FLT_MAX));
    v = fminf(v, dpp_mv<ROW_SHR8>(v, FLT_MAX));
    v = fminf(v, dpp_mv<ROW_BCAST15>(v, FLT_MAX));
    v = fminf(v, dpp_mv<ROW_BCAST31>(v, FLT_MAX));
    return readlane_f(v, 63);
}
// half-wave reductions: totals at lane 31 (lower) and lane 63 (upper)
__device__ __forceinline__ float half_max(float v) {
    v = fmaxf(v, dpp_mv<ROW_SHR1>(v, -FLT_MAX));
    v = fmaxf(v, dpp_mv<ROW_SHR2>(v, -FLT_MAX));
    v = fmaxf(v, dpp_mv<ROW_SHR4>(v, -FLT_MAX));
    v = fmaxf(v, dpp_mv<ROW_SHR8>(v, -FLT_MAX));
    v = fmaxf(v, dpp_mv<ROW_BCAST15>(v, -FLT_MAX));
    return v;
}
__device__ __forceinline__ float half_sum(float v) {
    v += dpp_mv<ROW_SHR1>(v, 0.f);
    v += dpp_mv<ROW_SHR2>(v, 0.f);
    v += dpp_mv<ROW_SHR4>(v, 0.f);
    v += dpp_mv<ROW_SHR8>(v, 0.f);
    v += dpp_mv<ROW_BCAST15>(v, 0.f);
    return v;
}

// med3-based sorted insert of (v, mi) into ascending (q[R][0..3], ji[R][0..3]).
// Exactly equivalent to the cmp/sel chain (strict-<, equal values keep
// incumbent first): insert position = first k with v < q_k; values via
// c0'=min(c0,v), ck'=med3(c_{k-1}, v, c_k).
#define INS4M(R, V, MI)                                                  \
    {   const float v_ = (V); const int mi_ = (MI);                      \
        const bool f0_ = v_ < q[R][0];                                   \
        const bool f1_ = v_ < q[R][1];                                   \
        const bool f2_ = v_ < q[R][2];                                   \
        const bool f3_ = v_ < q[R][3];                                   \
        const float n0_ = fminf(q[R][0], v_);                            \
        const float n1_ = __builtin_amdgcn_fmed3f(q[R][0], v_, q[R][1]); \
        const float n2_ = __builtin_amdgcn_fmed3f(q[R][1], v_, q[R][2]); \
        const float n3_ = __builtin_amdgcn_fmed3f(q[R][2], v_, q[R][3]); \
        const int t1_ = f0_ ? ji[R][0] : mi_;                            \
        const int t2_ = f1_ ? ji[R][1] : mi_;                            \
        const int t3_ = f2_ ? ji[R][2] : mi_;                            \
        ji[R][0] = f0_ ? mi_ : ji[R][0];                                 \
        ji[R][1] = f1_ ? t1_ : ji[R][1];                                 \
        ji[R][2] = f2_ ? t2_ : ji[R][2];                                 \
        ji[R][3] = f3_ ? t3_ : ji[R][3];                                 \
        q[R][0] = n0_; q[R][1] = n1_; q[R][2] = n2_; q[R][3] = n3_;      \
    }

// Chunk processing: batch-compute 8 distances into regs, then med3-inserts.
#define PROC_CHUNK(PX, PY, PZ, CH)                                      \
    {   const int mbase_ = ((CH) << 8) + (lane << 2);                   \
        float vv0[4], vv1[4];                                           \
        _Pragma("unroll")                                               \
        for (int c = 0; c < 4; ++c) {                                   \
            const float mx = PX[c], my = PY[c], mz = PZ[c];             \
            const float mxx = mx*mx + my*my + mz*mz;                    \
            {   float inner = cx[0]*mx + cy[0]*my + cz[0]*mz;           \
                vv0[c] = mxx - (2.0f * inner - xx[0]); }                \
            {   float inner = cx[1]*mx + cy[1]*my + cz[1]*mz;           \
                vv1[c] = mxx - (2.0f * inner - xx[1]); }                \
        }                                                               \
        _Pragma("unroll")                                               \
        for (int c = 0; c < 4; ++c) {                                   \
            const int mi = mbase_ + c;                                  \
            INS4M(0, vv0[c], mi)                                        \
            INS4M(1, vv1[c], mi)                                        \
        }                                                               \
    }

// load one chunk from GLOBAL (L2-resident cloud), coalesced float4
#define LOAD_CHUNK(PX, PY, PZ, CH)                                      \
    {   const int f4i_ = (((CH) & (NCHUNK - 1)) << 6) + lane;           \
        *(float4*)PX = g4[f4i_];                                        \
        *(float4*)PY = g4[f4i_ + 1024];                                 \
        *(float4*)PZ = g4[f4i_ + 2048];                                 \
    }

__global__ __launch_bounds__(1024, 4)
void lae_kernel(const float* __restrict__ x,
                const float* __restrict__ w1, const float* __restrict__ b1,
                const float* __restrict__ w2, const float* __restrict__ b2,
                const float* __restrict__ w3, const float* __restrict__ b3,
                float* __restrict__ out)
{
    __shared__ int s_nbr[ROWSB][KNN];     // 2.5 KB — the only LDS

    const int tid  = threadIdx.x;
    const int lane = tid & 63;
    const int wid  = tid >> 6;            // 0..15
    const int b    = blockIdx.y;
    const int rbase = blockIdx.x * ROWSB + wid * RPW;

    const float* xb = x + (size_t)b * 3 * NPTS;
    const float4* g4 = (const float4*)xb;

    float cx[RPW], cy[RPW], cz[RPW], xx[RPW];
    #pragma unroll
    for (int r = 0; r < RPW; ++r) {
        cx[r] = xb[rbase + r];
        cy[r] = xb[rbase + r + NPTS];
        cz[r] = xb[rbase + r + 2 * NPTS];
        xx[r] = cx[r]*cx[r] + cy[r]*cy[r] + cz[r]*cz[r];
    }

    float q[RPW][4];
    int   ji[RPW][4];
    #pragma unroll
    for (int r = 0; r < RPW; ++r)
        #pragma unroll
        for (int s = 0; s < 4; ++s) { q[r][s] = FLT_MAX; ji[r][s] = -1; }

    // --- pass 1: register-double-buffered chunks streamed from L2 ---
    float pxA[4], pyA[4], pzA[4], pxB[4], pyB[4], pzB[4];
    LOAD_CHUNK(pxA, pyA, pzA, 0)
    #pragma unroll 1
    for (int ch = 0; ch < NCHUNK; ch += 2) {
        LOAD_CHUNK(pxB, pyB, pzB, ch + 1)     // prefetch odd chunk
        PROC_CHUNK(pxA, pyA, pzA, ch)
        LOAD_CHUNK(pxA, pyA, pzA, ch + 2)     // prefetch next even (wraps, harmless)
        PROC_CHUNK(pxB, pyB, pzB, ch + 1)
    }

    // --- extraction: 20 x interleaved {wave-min, pop} for RPW rows ---
    int cnt[RPW] = {4, 4};
    for (int t = 0; t < KNN; ++t) {
        float g[RPW]; int win[RPW]; int midx[RPW];
        #pragma unroll
        for (int r = 0; r < RPW; ++r) g[r] = wave_min_bcast(q[r][0]);
        #pragma unroll
        for (int r = 0; r < RPW; ++r) {
            unsigned long long mk = __ballot(q[r][0] == g[r]);
            win[r]  = (int)__builtin_ctzll(mk);
            midx[r] = __builtin_amdgcn_readlane(ji[r][0], win[r]);
        }
        if (lane == 0) {
            #pragma unroll
            for (int r = 0; r < RPW; ++r) s_nbr[wid * RPW + r][t] = midx[r];
        }
        #pragma unroll
        for (int r = 0; r < RPW; ++r) {
            if (lane == win[r]) {
                q[r][0] = q[r][1]; ji[r][0] = ji[r][1];
                q[r][1] = q[r][2]; ji[r][1] = ji[r][2];
                q[r][2] = q[r][3]; ji[r][2] = ji[r][3];
                q[r][3] = FLT_MAX; ji[r][3] = -1;
                cnt[r]--;
            }
        }
        #pragma unroll
        for (int r = 0; r < RPW; ++r) {
            if (cnt[r] == 0) {
                // rare: rebuild lane's top-4 minus emitted; SAME per-lane
                // candidate set as pass 1 (mi = ch*256 + lane*4 + c), scalar global reads
                q[r][0] = FLT_MAX; q[r][1] = FLT_MAX; q[r][2] = FLT_MAX; q[r][3] = FLT_MAX;
                ji[r][0] = -1; ji[r][1] = -1; ji[r][2] = -1; ji[r][3] = -1;
                for (int j = 0; j < 64; ++j) {
                    const int mi = ((j >> 2) << 8) + (lane << 2) + (j & 3);
                    bool ex = false;
                    for (int e = 0; e <= t; ++e)
                        ex = ex || (s_nbr[wid * RPW + r][e] == mi);
                    if (!ex) {
                        float mx = xb[mi], my = xb[mi + NPTS], mz = xb[mi + 2*NPTS];
                        float inner = cx[r]*mx + cy[r]*my + cz[r]*mz;
                        float mxx   = mx*mx + my*my + mz*mz;
                        float v = mxx - (2.0f * inner - xx[r]);
                        INS4M(r, v, mi)
                    }
                }
                cnt[r] = 4;
            }
        }
    }

    // --- epilogue: half-wave split (lanes 0-31 = row 0, 32-63 = row 1) ---
    const int  kh    = lane & 31;
    const bool lower = (lane < 32);
    const bool valid = (kh < KNN);
    const int  kk    = valid ? kh : 0;

    const float ex = lower ? cx[0] : cx[1];
    const float ey = lower ? cy[0] : cy[1];
    const float ez = lower ? cz[0] : cz[1];
    const int rib  = wid * RPW + (lower ? 0 : 1);
    const int nrow = rbase + (lower ? 0 : 1);

    float sa = b3[0];
    #pragma unroll
    for (int o = 0; o < 16; ++o) {
        float f = b1[o] + w1[o*3+0]*ex + w1[o*3+1]*ey + w1[o*3+2]*ez;
        sa += w3[o] * f;
    }

    const int m = s_nbr[rib][kk];
    float dx = ex - xb[m], dy = ey - xb[m + NPTS], dz = ez - xb[m + 2*NPTS];
    float x1v[16];
    float na = b3[0];
    #pragma unroll
    for (int o = 0; o < 16; ++o) {
        float t2 = b2[o] + w2[o*3+0]*dx + w2[o*3+1]*dy + w2[o*3+2]*dz;
        x1v[o] = t2;
        na += w3[o] * t2;
    }
    float logit = sa + na;
    float l = (logit >= 0.f) ? logit : 0.01f * logit;   // leaky_relu(0.01)

    float hm  = half_max(valid ? l : -FLT_MAX);
    float lm  = lower ? readlane_f(hm, 31) : readlane_f(hm, 63);
    float pr  = valid ? expf(l - lm) : 0.f;
    float hs  = half_sum(pr);
    float ps  = lower ? readlane_f(hs, 31) : readlane_f(hs, 63);
    float coef = pr / ps;

    float res = 0.f;
    #pragma unroll
    for (int o = 0; o < 16; ++o) {
        float s  = half_sum(coef * x1v[o]);
        float sv = lower ? readlane_f(s, 31) : readlane_f(s, 63);
        res = (kh == o) ? sv : res;
    }
    if (kh < 16) {
        float r2 = (res > 0.f) ? res : expm1f(res);     // elu
        out[((size_t)b * 16 + kh) * NPTS + nrow] = r2;
    }
}

extern "C" void kernel_launch(void* const* d_in, const int* in_sizes, int n_in,
                              void* d_out, int out_size, void* d_ws, size_t ws_size,
                              hipStream_t stream)
{
    const float* x  = (const float*)d_in[0];
    const float* w1 = (const float*)d_in[1];
    const float* b1 = (const float*)d_in[2];
    const float* w2 = (const float*)d_in[3];
    const float* b2 = (const float*)d_in[4];
    const float* w3 = (const float*)d_in[5];
    const float* b3 = (const float*)d_in[6];
    float* out = (float*)d_out;

    dim3 grid(NPTS / ROWSB, 16, 1);
    lae_kernel<<<grid, dim3(1024, 1, 1), 0, stream>>>(x, w1, b1, w2, b2, w3, b3, out);
}

// Round 19
// 331.968 us; speedup vs baseline: 1.2603x; 1.2603x over previous
//
#include <hip/hip_runtime.h>
#include <math.h>
#include <float.h>

#define NPTS 4096
#define KNN  20
#define RPW  2                  // rows per wave
#define WAVES 4                 // waves per block (256 threads)
#define ROWSB (WAVES * RPW)     // 8 rows per block
#define NCHUNK (NPTS / 256)     // 16 chunks of 256 candidates (4 per lane)

#define ROW_SHR1    0x111
#define ROW_SHR2    0x112
#define ROW_SHR4    0x114
#define ROW_SHR8    0x118
#define ROW_BCAST15 0x142
#define ROW_BCAST31 0x143

template <int CTRL>
__device__ __forceinline__ float dpp_mv(float x, float ident) {
    int r = __builtin_amdgcn_update_dpp(__float_as_int(ident), __float_as_int(x),
                                        CTRL, 0xf, 0xf, false);
    return __int_as_float(r);
}
__device__ __forceinline__ float readlane_f(float v, int l) {
    return __int_as_float(__builtin_amdgcn_readlane(__float_as_int(v), l));
}
__device__ __forceinline__ float wave_min_bcast(float v) {
    v = fminf(v, dpp_mv<ROW_SHR1>(v, FLT_MAX));
    v = fminf(v, dpp_mv<ROW_SHR2>(v, FLT_MAX));
    v = fminf(v, dpp_mv<ROW_SHR4>(v, FLT_MAX));
    v = fminf(v, dpp_mv<ROW_SHR8>(v, FLT_MAX));
    v = fminf(v, dpp_mv<ROW_BCAST15>(v, FLT_MAX));
    v = fminf(v, dpp_mv<ROW_BCAST31>(v, FLT_MAX));
    return readlane_f(v, 63);
}
// half-wave reductions: totals at lane 31 (lower) and lane 63 (upper)
__device__ __forceinline__ float half_max(float v) {
    v = fmaxf(v, dpp_mv<ROW_SHR1>(v, -FLT_MAX));
    v = fmaxf(v, dpp_mv<ROW_SHR2>(v, -FLT_MAX));
    v = fmaxf(v, dpp_mv<ROW_SHR4>(v, -FLT_MAX));
    v = fmaxf(v, dpp_mv<ROW_SHR8>(v, -FLT_MAX));
    v = fmaxf(v, dpp_mv<ROW_BCAST15>(v, -FLT_MAX));
    return v;
}
__device__ __forceinline__ float half_sum(float v) {
    v += dpp_mv<ROW_SHR1>(v, 0.f);
    v += dpp_mv<ROW_SHR2>(v, 0.f);
    v += dpp_mv<ROW_SHR4>(v, 0.f);
    v += dpp_mv<ROW_SHR8>(v, 0.f);
    v += dpp_mv<ROW_BCAST15>(v, 0.f);
    return v;
}

// med3-based sorted insert of (v, mi) into ascending (q[R][0..3], ji[R][0..3]).
// Exactly equivalent to the cmp/sel chain (strict-<, equal values keep
// incumbent first): insert position = first k with v < q_k; values via
// c0'=min(c0,v), ck'=med3(c_{k-1}, v, c_k).
#define INS4M(R, V, MI)                                                  \
    {   const float v_ = (V); const int mi_ = (MI);                      \
        const bool f0_ = v_ < q[R][0];                                   \
        const bool f1_ = v_ < q[R][1];                                   \
        const bool f2_ = v_ < q[R][2];                                   \
        const bool f3_ = v_ < q[R][3];                                   \
        const float n0_ = fminf(q[R][0], v_);                            \
        const float n1_ = __builtin_amdgcn_fmed3f(q[R][0], v_, q[R][1]); \
        const float n2_ = __builtin_amdgcn_fmed3f(q[R][1], v_, q[R][2]); \
        const float n3_ = __builtin_amdgcn_fmed3f(q[R][2], v_, q[R][3]); \
        const int t1_ = f0_ ? ji[R][0] : mi_;                            \
        const int t2_ = f1_ ? ji[R][1] : mi_;                            \
        const int t3_ = f2_ ? ji[R][2] : mi_;                            \
        ji[R][0] = f0_ ? mi_ : ji[R][0];                                 \
        ji[R][1] = f1_ ? t1_ : ji[R][1];                                 \
        ji[R][2] = f2_ ? t2_ : ji[R][2];                                 \
        ji[R][3] = f3_ ? t3_ : ji[R][3];                                 \
        q[R][0] = n0_; q[R][1] = n1_; q[R][2] = n2_; q[R][3] = n3_;      \
    }

// Chunk processing: batch-compute 8 distances into regs, then med3-inserts.
#define PROC_CHUNK(PX, PY, PZ, CH)                                      \
    {   const int mbase_ = ((CH) << 8) + (lane << 2);                   \
        float vv0[4], vv1[4];                                           \
        _Pragma("unroll")                                               \
        for (int c = 0; c < 4; ++c) {                                   \
            const float mx = PX[c], my = PY[c], mz = PZ[c];             \
            const float mxx = mx*mx + my*my + mz*mz;                    \
            {   float inner = cx[0]*mx + cy[0]*my + cz[0]*mz;           \
                vv0[c] = mxx - (2.0f * inner - xx[0]); }                \
            {   float inner = cx[1]*mx + cy[1]*my + cz[1]*mz;           \
                vv1[c] = mxx - (2.0f * inner - xx[1]); }                \
        }                                                               \
        _Pragma("unroll")                                               \
        for (int c = 0; c < 4; ++c) {                                   \
            const int mi = mbase_ + c;                                  \
            INS4M(0, vv0[c], mi)                                        \
            INS4M(1, vv1[c], mi)                                        \
        }                                                               \
    }

// load one chunk from GLOBAL (L2-resident cloud), coalesced float4
#define LOAD_CHUNK(PX, PY, PZ, CH)                                      \
    {   const int f4i_ = (((CH) & (NCHUNK - 1)) << 6) + lane;           \
        *(float4*)PX = g4[f4i_];                                        \
        *(float4*)PY = g4[f4i_ + 1024];                                 \
        *(float4*)PZ = g4[f4i_ + 2048];                                 \
    }

__global__
void lae_kernel(const float* __restrict__ x,
                const float* __restrict__ w1, const float* __restrict__ b1,
                const float* __restrict__ w2, const float* __restrict__ b2,
                const float* __restrict__ w3, const float* __restrict__ b3,
                float* __restrict__ out)
{
    __shared__ int s_nbr[ROWSB][KNN];     // 640 B — the only LDS

    const int tid  = threadIdx.x;
    const int lane = tid & 63;
    const int wid  = tid >> 6;            // 0..3
    const int b    = blockIdx.y;
    const int rbase = blockIdx.x * ROWSB + wid * RPW;

    const float* xb = x + (size_t)b * 3 * NPTS;
    const float4* g4 = (const float4*)xb;

    float cx[RPW], cy[RPW], cz[RPW], xx[RPW];
    #pragma unroll
    for (int r = 0; r < RPW; ++r) {
        cx[r] = xb[rbase + r];
        cy[r] = xb[rbase + r + NPTS];
        cz[r] = xb[rbase + r + 2 * NPTS];
        xx[r] = cx[r]*cx[r] + cy[r]*cy[r] + cz[r]*cz[r];
    }

    float q[RPW][4];
    int   ji[RPW][4];
    #pragma unroll
    for (int r = 0; r < RPW; ++r)
        #pragma unroll
        for (int s = 0; s < 4; ++s) { q[r][s] = FLT_MAX; ji[r][s] = -1; }

    // --- pass 1: register-double-buffered chunks streamed from L2 ---
    float pxA[4], pyA[4], pzA[4], pxB[4], pyB[4], pzB[4];
    LOAD_CHUNK(pxA, pyA, pzA, 0)
    #pragma unroll 1
    for (int ch = 0; ch < NCHUNK; ch += 2) {
        LOAD_CHUNK(pxB, pyB, pzB, ch + 1)     // prefetch odd chunk
        PROC_CHUNK(pxA, pyA, pzA, ch)
        LOAD_CHUNK(pxA, pyA, pzA, ch + 2)     // prefetch next even (wraps, harmless)
        PROC_CHUNK(pxB, pyB, pzB, ch + 1)
    }

    // --- extraction: 20 x interleaved {wave-min, pop} for RPW rows ---
    int cnt[RPW] = {4, 4};
    for (int t = 0; t < KNN; ++t) {
        float g[RPW]; int win[RPW]; int midx[RPW];
        #pragma unroll
        for (int r = 0; r < RPW; ++r) g[r] = wave_min_bcast(q[r][0]);
        #pragma unroll
        for (int r = 0; r < RPW; ++r) {
            unsigned long long mk = __ballot(q[r][0] == g[r]);
            win[r]  = (int)__builtin_ctzll(mk);
            midx[r] = __builtin_amdgcn_readlane(ji[r][0], win[r]);
        }
        if (lane == 0) {
            #pragma unroll
            for (int r = 0; r < RPW; ++r) s_nbr[wid * RPW + r][t] = midx[r];
        }
        #pragma unroll
        for (int r = 0; r < RPW; ++r) {
            if (lane == win[r]) {
                q[r][0] = q[r][1]; ji[r][0] = ji[r][1];
                q[r][1] = q[r][2]; ji[r][1] = ji[r][2];
                q[r][2] = q[r][3]; ji[r][2] = ji[r][3];
                q[r][3] = FLT_MAX; ji[r][3] = -1;
                cnt[r]--;
            }
        }
        #pragma unroll
        for (int r = 0; r < RPW; ++r) {
            if (cnt[r] == 0) {
                // rare: rebuild lane's top-4 minus emitted; SAME per-lane
                // candidate set as pass 1 (mi = ch*256 + lane*4 + c), scalar global reads
                q[r][0] = FLT_MAX; q[r][1] = FLT_MAX; q[r][2] = FLT_MAX; q[r][3] = FLT_MAX;
                ji[r][0] = -1; ji[r][1] = -1; ji[r][2] = -1; ji[r][3] = -1;
                for (int j = 0; j < 64; ++j) {
                    const int mi = ((j >> 2) << 8) + (lane << 2) + (j & 3);
                    bool ex = false;
                    for (int e = 0; e <= t; ++e)
                        ex = ex || (s_nbr[wid * RPW + r][e] == mi);
                    if (!ex) {
                        float mx = xb[mi], my = xb[mi + NPTS], mz = xb[mi + 2*NPTS];
                        float inner = cx[r]*mx + cy[r]*my + cz[r]*mz;
                        float mxx   = mx*mx + my*my + mz*mz;
                        float v = mxx - (2.0f * inner - xx[r]);
                        INS4M(r, v, mi)
                    }
                }
                cnt[r] = 4;
            }
        }
    }

    // --- epilogue: half-wave split (lanes 0-31 = row 0, 32-63 = row 1) ---
    const int  kh    = lane & 31;
    const bool lower = (lane < 32);
    const bool valid = (kh < KNN);
    const int  kk    = valid ? kh : 0;

    const float ex = lower ? cx[0] : cx[1];
    const float ey = lower ? cy[0] : cy[1];
    const float ez = lower ? cz[0] : cz[1];
    const int rib  = wid * RPW + (lower ? 0 : 1);
    const int nrow = rbase + (lower ? 0 : 1);

    float sa = b3[0];
    #pragma unroll
    for (int o = 0; o < 16; ++o) {
        float f = b1[o] + w1[o*3+0]*ex + w1[o*3+1]*ey + w1[o*3+2]*ez;
        sa += w3[o] * f;
    }

    const int m = s_nbr[rib][kk];
    float dx = ex - xb[m], dy = ey - xb[m + NPTS], dz = ez - xb[m + 2*NPTS];
    float x1v[16];
    float na = b3[0];
    #pragma unroll
    for (int o = 0; o < 16; ++o) {
        float t2 = b2[o] + w2[o*3+0]*dx + w2[o*3+1]*dy + w2[o*3+2]*dz;
        x1v[o] = t2;
        na += w3[o] * t2;
    }
    float logit = sa + na;
    float l = (logit >= 0.f) ? logit : 0.01f * logit;   // leaky_relu(0.01)

    float hm  = half_max(valid ? l : -FLT_MAX);
    float lm  = lower ? readlane_f(hm, 31) : readlane_f(hm, 63);
    float pr  = valid ? expf(l - lm) : 0.f;
    float hs  = half_sum(pr);
    float ps  = lower ? readlane_f(hs, 31) : readlane_f(hs, 63);
    float coef = pr / ps;

    float res = 0.f;
    #pragma unroll
    for (int o = 0; o < 16; ++o) {
        float s  = half_sum(coef * x1v[o]);
        float sv = lower ? readlane_f(s, 31) : readlane_f(s, 63);
        res = (kh == o) ? sv : res;
    }
    if (kh < 16) {
        float r2 = (res > 0.f) ? res : expm1f(res);     // elu
        out[((size_t)b * 16 + kh) * NPTS + nrow] = r2;
    }
}

extern "C" void kernel_launch(void* const* d_in, const int* in_sizes, int n_in,
                              void* d_out, int out_size, void* d_ws, size_t ws_size,
                              hipStream_t stream)
{
    const float* x  = (const float*)d_in[0];
    const float* w1 = (const float*)d_in[1];
    const float* b1 = (const float*)d_in[2];
    const float* w2 = (const float*)d_in[3];
    const float* b2 = (const float*)d_in[4];
    const float* w3 = (const float*)d_in[5];
    const float* b3 = (const float*)d_in[6];
    float* out = (float*)d_out;

    dim3 grid(NPTS / ROWSB, 16, 1);
    lae_kernel<<<grid, dim3(256, 1, 1), 0, stream>>>(x, w1, b1, w2, b2, w3, b3, out);
}